// Round 7
// baseline (1563.202 us; speedup 1.0000x reference)
//
#include <hip/hip_runtime.h>
#include <math.h>

// GCN forward, bucketed-gather formulation.
// Measured facts driving this design (R4/R5/R6 counters):
//   - device-scope atomics cost ~30-45ns + ~30-60B fabric traffic EACH,
//     independent of XCD locality -> must minimize atomic COUNT.
//   - scattered 4B stores to a region shared by all XCDs thrash lines (~7x
//     write amplification); block-local contiguous runs are L2-absorbed.
// Build: k_bin bins edges by dst-bucket (128 nodes) with LDS histograms; ONE
//   global atomic per (block,bucket) run reservation (~153k vs 3.2M), packed
//   edge = (dst&127)<<17 | src (src < 2^17). Runs are block-private -> clean.
// Degree: per-bucket LDS histogram, zero global atomics.
// Per layer: GEMM writes hWs = dinv[r]*(feat @ W); bucket-gather accumulates
//   sum(hWs[src]) into a 16KB LDS tile via ds_add_f32, epilogue
//   agg = b + dinv[d]*(hWs[d] + sum)  (self-loop+bias folded). Layer-2 gather
//   fuses the score head via 32-lane shfl reduce.

static inline int cdiv(long a, int b) { return (int)((a + (long)b - 1) / b); }

#define EPB 16384     // edges per k_bin block
#define BUKMAX 1024   // max buckets (N<=131072)
#define CAP 4608      // per-bucket capacity; E[deg_bucket]=4096, 8 sigma pad

// --- binning build: LDS hist -> 1 reservation atomic per (block,bucket) -> run fill
__global__ __launch_bounds__(256) void k_bin(const int* __restrict__ src,
                                             const int* __restrict__ dst,
                                             unsigned* __restrict__ gcur,
                                             unsigned* __restrict__ ebuf,
                                             int E, int nbuk) {
  __shared__ unsigned lhist[BUKMAX];
  __shared__ unsigned gbase[BUKMAX];
  __shared__ unsigned lcur[BUKMAX];
  int tid = threadIdx.x;
  for (int i = tid; i < nbuk; i += 256) { lhist[i] = 0; lcur[i] = 0; }
  __syncthreads();
  int e0 = blockIdx.x * EPB;
  int e1 = min(e0 + EPB, E);
  for (int e = e0 + tid; e < e1; e += 256) {
    int d = __builtin_nontemporal_load(&dst[e]);
    atomicAdd(&lhist[d >> 7], 1u);
  }
  __syncthreads();
  for (int b = tid; b < nbuk; b += 256) {
    unsigned n = lhist[b];
    gbase[b] = n ? atomicAdd(&gcur[b], n) : 0u;
  }
  __syncthreads();
  for (int e = e0 + tid; e < e1; e += 256) {
    int d = __builtin_nontemporal_load(&dst[e]);
    int s = __builtin_nontemporal_load(&src[e]);
    int b = d >> 7;
    unsigned off = gbase[b] + atomicAdd(&lcur[b], 1u);
    if (off < CAP)  // overflow guard, P ~ 1e-11
      ebuf[(size_t)b * CAP + off] = ((unsigned)(d & 127) << 17) | (unsigned)s;
  }
}

// --- per-bucket degree -> dinv, zero global atomics
__global__ __launch_bounds__(256) void k_deg(const unsigned* __restrict__ gcur,
                                             const unsigned* __restrict__ ebuf,
                                             float* __restrict__ dinv, int N) {
  __shared__ unsigned lc[128];
  int b = blockIdx.x, tid = threadIdx.x;
  if (tid < 128) lc[tid] = 0;
  __syncthreads();
  int cnt = min((int)gcur[b], CAP);
  const unsigned* eb = ebuf + (size_t)b * CAP;
  for (int j = tid; j < cnt; j += 256) atomicAdd(&lc[eb[j] >> 17], 1u);
  __syncthreads();
  if (tid < 128) {
    int node = (b << 7) + tid;
    if (node < N) dinv[node] = rsqrtf((float)lc[tid] + 1.0f);
  }
}

// hWs = dinv[r] * (x @ W1)   (x: [N,128], W1: [128,32])
__global__ __launch_bounds__(256) void k_gemm1(
    const float* __restrict__ x, const float* __restrict__ W1,
    const float* __restrict__ dinv, float* __restrict__ hWs, int N) {
  __shared__ float w[128 * 32];
  for (int i = threadIdx.x; i < 128 * 32; i += 256) w[i] = W1[i];
  __syncthreads();
  int gid = blockIdx.x * 256 + threadIdx.x;
  int r = gid >> 5, c = gid & 31;
  if (r >= N) return;
  const float4* xr = (const float4*)(x + (size_t)r * 128);
  float acc = 0.f;
#pragma unroll
  for (int k4 = 0; k4 < 32; ++k4) {
    float4 xv = xr[k4];
    acc = fmaf(xv.x, w[(k4 * 4 + 0) * 32 + c], acc);
    acc = fmaf(xv.y, w[(k4 * 4 + 1) * 32 + c], acc);
    acc = fmaf(xv.z, w[(k4 * 4 + 2) * 32 + c], acc);
    acc = fmaf(xv.w, w[(k4 * 4 + 3) * 32 + c], acc);
  }
  hWs[gid] = dinv[r] * acc;
}

// hWs = dinv[r] * (relu(h) @ W2)   (h: [N,32] pre-ReLU, W2: [32,32])
__global__ __launch_bounds__(256) void k_gemm2(
    const float* __restrict__ h, const float* __restrict__ W2,
    const float* __restrict__ dinv, float* __restrict__ hWs, int N) {
  __shared__ float w[32 * 32];
  for (int i = threadIdx.x; i < 32 * 32; i += 256) w[i] = W2[i];
  __syncthreads();
  int gid = blockIdx.x * 256 + threadIdx.x;
  int r = gid >> 5, c = gid & 31;
  if (r >= N) return;
  const float4* hr = (const float4*)(h + (size_t)r * 32);
  float acc = 0.f;
#pragma unroll
  for (int k4 = 0; k4 < 8; ++k4) {
    float4 v = hr[k4];
    acc = fmaf(fmaxf(v.x, 0.f), w[(k4 * 4 + 0) * 32 + c], acc);
    acc = fmaf(fmaxf(v.y, 0.f), w[(k4 * 4 + 1) * 32 + c], acc);
    acc = fmaf(fmaxf(v.z, 0.f), w[(k4 * 4 + 2) * 32 + c], acc);
    acc = fmaf(fmaxf(v.w, 0.f), w[(k4 * 4 + 3) * 32 + c], acc);
  }
  hWs[gid] = dinv[r] * acc;
}

// layer-1 bucket gather: h[d,c] = b[c] + dinv[d]*(hWs[d,c] + sum_edges hWs[s,c])
// one block per bucket; 16KB LDS tile; half-wave (32 lanes) per edge.
__global__ __launch_bounds__(256) void k_agg1(
    const unsigned* __restrict__ gcur, const unsigned* __restrict__ ebuf,
    const float* __restrict__ dinv, const float* __restrict__ hWs,
    const float* __restrict__ bias, float* __restrict__ h, int N) {
  __shared__ float lagg[128 * 32];
  int b = blockIdx.x, tid = threadIdx.x;
  for (int t = tid; t < 4096; t += 256) lagg[t] = 0.f;
  __syncthreads();
  int cnt = min((int)gcur[b], CAP);
  const unsigned* eb = ebuf + (size_t)b * CAP;
  int c = tid & 31;
  int slot = tid >> 5;  // 8 half-waves
  int j = slot;
  for (; j + 8 < cnt; j += 16) {
    unsigned p0 = eb[j];
    unsigned p1 = eb[j + 8];
    float v0 = hWs[(size_t)(p0 & 0x1FFFF) * 32 + c];
    float v1 = hWs[(size_t)(p1 & 0x1FFFF) * 32 + c];
    atomicAdd(&lagg[((p0 >> 17) << 5) + c], v0);
    atomicAdd(&lagg[((p1 >> 17) << 5) + c], v1);
  }
  if (j < cnt) {
    unsigned p = eb[j];
    atomicAdd(&lagg[((p >> 17) << 5) + c], hWs[(size_t)(p & 0x1FFFF) * 32 + c]);
  }
  __syncthreads();
  int nbase = b << 7;
  for (int t = tid; t < 4096; t += 256) {
    int node = nbase + (t >> 5);
    int cc = t & 31;
    if (node < N)
      h[(size_t)node * 32 + cc] =
          fmaf(dinv[node], hWs[(size_t)node * 32 + cc] + lagg[t], bias[cc]);
  }
}

// layer-2 bucket gather + fused score head:
// scores[1+d] = sum_c relu(agg2[d,c]) * Wh[c] + bh
__global__ __launch_bounds__(256) void k_agg2_score(
    const unsigned* __restrict__ gcur, const unsigned* __restrict__ ebuf,
    const float* __restrict__ dinv, const float* __restrict__ hWs,
    const float* __restrict__ bias, const float* __restrict__ Wh,
    const float* __restrict__ bh, const float* __restrict__ cash,
    float* __restrict__ scores, int N) {
  __shared__ float lagg[128 * 32];
  int b = blockIdx.x, tid = threadIdx.x;
  if (b == 0 && tid == 0) scores[0] = cash[0];
  for (int t = tid; t < 4096; t += 256) lagg[t] = 0.f;
  __syncthreads();
  int cnt = min((int)gcur[b], CAP);
  const unsigned* eb = ebuf + (size_t)b * CAP;
  int c = tid & 31;
  int slot = tid >> 5;
  int j = slot;
  for (; j + 8 < cnt; j += 16) {
    unsigned p0 = eb[j];
    unsigned p1 = eb[j + 8];
    float v0 = hWs[(size_t)(p0 & 0x1FFFF) * 32 + c];
    float v1 = hWs[(size_t)(p1 & 0x1FFFF) * 32 + c];
    atomicAdd(&lagg[((p0 >> 17) << 5) + c], v0);
    atomicAdd(&lagg[((p1 >> 17) << 5) + c], v1);
  }
  if (j < cnt) {
    unsigned p = eb[j];
    atomicAdd(&lagg[((p >> 17) << 5) + c], hWs[(size_t)(p & 0x1FFFF) * 32 + c]);
  }
  __syncthreads();
  int nbase = b << 7;
  for (int t = tid; t < 4096; t += 256) {
    int node = nbase + (t >> 5);
    int cc = t & 31;
    float val = 0.f;
    if (node < N)
      val = fmaf(dinv[node], hWs[(size_t)node * 32 + cc] + lagg[t], bias[cc]);
    float tc = fmaxf(val, 0.f) * Wh[cc];
#pragma unroll
    for (int m = 16; m >= 1; m >>= 1) tc += __shfl_xor(tc, m, 32);
    if (cc == 0 && node < N) scores[1 + node] = tc + bh[0];
  }
}

// --- softmax over N+1 scores ---
__global__ void k_red_max(const float* __restrict__ s, int n, float* __restrict__ part) {
  float m = -3.4e38f;
  for (int i = blockIdx.x * blockDim.x + threadIdx.x; i < n; i += gridDim.x * blockDim.x)
    m = fmaxf(m, s[i]);
  __shared__ float sm[256];
  sm[threadIdx.x] = m;
  __syncthreads();
  for (int o = 128; o > 0; o >>= 1) {
    if (threadIdx.x < o) sm[threadIdx.x] = fmaxf(sm[threadIdx.x], sm[threadIdx.x + o]);
    __syncthreads();
  }
  if (threadIdx.x == 0) part[blockIdx.x] = sm[0];
}

__global__ void k_red_sumexp(const float* __restrict__ s, int n,
                             const float* __restrict__ mptr, float* __restrict__ part) {
  float m = *mptr;
  float acc = 0.f;
  for (int i = blockIdx.x * blockDim.x + threadIdx.x; i < n; i += gridDim.x * blockDim.x)
    acc += expf(s[i] - m);
  __shared__ float sm[256];
  sm[threadIdx.x] = acc;
  __syncthreads();
  for (int o = 128; o > 0; o >>= 1) {
    if (threadIdx.x < o) sm[threadIdx.x] += sm[threadIdx.x + o];
    __syncthreads();
  }
  if (threadIdx.x == 0) part[blockIdx.x] = sm[0];
}

__global__ void k_red_sum(const float* __restrict__ s, int n, float* __restrict__ outp) {
  float acc = 0.f;
  for (int i = threadIdx.x; i < n; i += blockDim.x) acc += s[i];
  __shared__ float sm[256];
  sm[threadIdx.x] = acc;
  __syncthreads();
  for (int o = 128; o > 0; o >>= 1) {
    if (threadIdx.x < o) sm[threadIdx.x] += sm[threadIdx.x + o];
    __syncthreads();
  }
  if (threadIdx.x == 0) *outp = sm[0];
}

__global__ void k_softmax_out(const float* __restrict__ s, int n,
                              const float* __restrict__ finals, float* __restrict__ out) {
  int i = blockIdx.x * 256 + threadIdx.x;
  if (i < n) out[i] = expf(s[i] - finals[0]) / finals[1];
}

extern "C" void kernel_launch(void* const* d_in, const int* in_sizes, int n_in,
                              void* d_out, int out_size, void* d_ws, size_t ws_size,
                              hipStream_t stream) {
  const float* x    = (const float*)d_in[0];
  const int*   ei   = (const int*)d_in[1];
  const float* W1   = (const float*)d_in[2];
  const float* b1   = (const float*)d_in[3];
  const float* W2   = (const float*)d_in[4];
  const float* b2   = (const float*)d_in[5];
  const float* Wh   = (const float*)d_in[6];
  const float* bh   = (const float*)d_in[7];
  const float* cash = (const float*)d_in[8];

  const int N = in_sizes[0] / 128;
  const int E = in_sizes[1] / 2;
  const int* src = ei;
  const int* dst = ei + E;
  const int nbuk = cdiv(N, 128);  // 782 for N=100000 (<= BUKMAX)

  char* p = (char*)d_ws;
  float* dinv   = (float*)p; p += sizeof(float) * N;
  float* hWs    = (float*)p; p += sizeof(float) * (size_t)N * 32;
  float* h1     = (float*)p; p += sizeof(float) * (size_t)N * 32;
  float* scores = (float*)p; p += sizeof(float) * (N + 1);
  float* part   = (float*)p; p += sizeof(float) * 256;
  float* finals = (float*)p; p += sizeof(float) * 4;
  unsigned* gcur = (unsigned*)p; p += sizeof(unsigned) * BUKMAX;
  unsigned* ebuf = (unsigned*)p; p += sizeof(unsigned) * (size_t)nbuk * CAP;
  float* out = (float*)d_out;
  const int n = N + 1;

  // --- adjacency build (shared by both layers) ---
  hipMemsetAsync(gcur, 0, sizeof(unsigned) * BUKMAX, stream);
  k_bin<<<cdiv(E, EPB), 256, 0, stream>>>(src, dst, gcur, ebuf, E, nbuk);
  k_deg<<<nbuk, 256, 0, stream>>>(gcur, ebuf, dinv, N);

  // --- layer 1 ---
  k_gemm1<<<cdiv((long)N * 32, 256), 256, 0, stream>>>(x, W1, dinv, hWs, N);
  k_agg1<<<nbuk, 256, 0, stream>>>(gcur, ebuf, dinv, hWs, b1, h1, N);

  // --- layer 2 (hWs overwritten after layer-1 consumption) ---
  k_gemm2<<<cdiv((long)N * 32, 256), 256, 0, stream>>>(h1, W2, dinv, hWs, N);
  k_agg2_score<<<nbuk, 256, 0, stream>>>(gcur, ebuf, dinv, hWs, b2, Wh, bh, cash, scores, N);

  // --- softmax ---
  k_red_max<<<256, 256, 0, stream>>>(scores, n, part);
  k_red_max<<<1, 256, 0, stream>>>(part, 256, finals);
  k_red_sumexp<<<256, 256, 0, stream>>>(scores, n, finals, part);
  k_red_sum<<<1, 256, 0, stream>>>(part, 256, finals + 1);
  k_softmax_out<<<cdiv(n, 256), 256, 0, stream>>>(scores, n, finals, out);
}

// Round 8
// 415.032 us; speedup vs baseline: 3.7665x; 3.7665x over previous
//
#include <hip/hip_runtime.h>
#include <math.h>

// GCN forward, gather formulation (R4 structure + measured refinements).
// Measured models driving this design:
//   R4/R5/R6: device-scope atomics cost per-op fabric traffic regardless of
//     XCD locality; hist(atomic-return)+fill(atomic-free scatter) beats any
//     fused or grouped variant.
//   R7: gather must be node-parallel (one 32-lane group per node, 3.2M lanes),
//     NOT bucket-parallel (782 blocks = latency-bound disaster).
// New this round:
//   - cnt padded to 1 counter per 64B line (cnt[d*16]) -> spread atomic RMW
//     over 100k lines instead of 6.4k (tests line-contention hypothesis).
//   - dinv folded into GEMM output: hWs = dinv[r]*(feat@W), so gather inner
//     loop is acc += hWs[s], no per-edge dinv load.
//     agg[d] = b + dinv[d]*(hWs[d] + sum_s hWs[s]).
//   - gather edge loop 4-deep unrolled (4 independent 128B loads in flight).
//   - layer-2 gather fuses score head (32-lane shfl reduce), no agg2/k_score.

static inline int cdiv(long a, int b) { return (int)((a + (long)b - 1) / b); }

#define CH 1024   // scan chunk per block
#define PAD 16    // ints per counter line (64B)

// cnt[d*PAD]++ and record this edge's arrival rank (coalesced store)
__global__ void k_hist(const int* __restrict__ dst, int* __restrict__ cnt,
                       int* __restrict__ myidx, int E) {
  int e = blockIdx.x * 256 + threadIdx.x;
  if (e < E) myidx[e] = atomicAdd(&cnt[(size_t)dst[e] * PAD], 1);
}

// exclusive scan of padded cnt into rowptr + per-block totals; also dinv.
__global__ __launch_bounds__(256) void k_scan1(const int* __restrict__ cnt, int n,
                                               int* __restrict__ outp,
                                               int* __restrict__ bsum,
                                               float* __restrict__ dinv) {
  __shared__ int tsum[256];
  int base = blockIdx.x * CH;
  int t = threadIdx.x;
  int v[4];
  int s = 0;
#pragma unroll
  for (int k = 0; k < 4; ++k) {
    int idx = base + t * 4 + k;
    int c = (idx < n) ? cnt[(size_t)idx * PAD] : 0;
    if (idx < n) dinv[idx] = rsqrtf((float)c + 1.0f);  // deg = c + self-loop
    v[k] = s;
    s += c;
  }
  tsum[t] = s;
  __syncthreads();
  for (int o = 1; o < 256; o <<= 1) {
    int val = (t >= o) ? tsum[t - o] : 0;
    __syncthreads();
    tsum[t] += val;
    __syncthreads();
  }
  int ex = (t == 0) ? 0 : tsum[t - 1];
#pragma unroll
  for (int k = 0; k < 4; ++k) {
    int idx = base + t * 4 + k;
    if (idx < n) outp[idx] = ex + v[k];
  }
  if (t == 255) bsum[blockIdx.x] = tsum[255];
}

// exclusive scan of bsum[0..nb) in-place (nb <= 256)
__global__ void k_scan2(int* __restrict__ bsum, int nb) {
  __shared__ int sm[256];
  int t = threadIdx.x;
  sm[t] = (t < nb) ? bsum[t] : 0;
  __syncthreads();
  for (int o = 1; o < 256; o <<= 1) {
    int val = (t >= o) ? sm[t - o] : 0;
    __syncthreads();
    sm[t] += val;
    __syncthreads();
  }
  if (t < nb) bsum[t] = (t == 0) ? 0 : sm[t - 1];
}

__global__ void k_scan3(int* __restrict__ rowptr, const int* __restrict__ bsumEx,
                        int n, int E) {
  int i = blockIdx.x * 256 + threadIdx.x;
  if (i < n) rowptr[i] += bsumEx[i / CH];
  if (i == 0) rowptr[n] = E;
}

// esrc grouped by dst: pos = rowptr[dst] + myidx[e]. Atomic-free scatter.
__global__ void k_fill(const int* __restrict__ src, const int* __restrict__ dst,
                       const int* __restrict__ rowptr, const int* __restrict__ myidx,
                       int* __restrict__ esrc, int E) {
  int e = blockIdx.x * 256 + threadIdx.x;
  if (e >= E) return;
  int d = dst[e];
  esrc[rowptr[d] + myidx[e]] = src[e];
}

// hWs = dinv[r] * (x @ W1)   (x: [N,128], W1: [128,32])
__global__ __launch_bounds__(256) void k_gemm1(
    const float* __restrict__ x, const float* __restrict__ W1,
    const float* __restrict__ dinv, float* __restrict__ hWs, int N) {
  __shared__ float w[128 * 32];
  for (int i = threadIdx.x; i < 128 * 32; i += 256) w[i] = W1[i];
  __syncthreads();
  int gid = blockIdx.x * 256 + threadIdx.x;
  int r = gid >> 5, c = gid & 31;
  if (r >= N) return;
  const float4* xr = (const float4*)(x + (size_t)r * 128);
  float acc = 0.f;
#pragma unroll
  for (int k4 = 0; k4 < 32; ++k4) {
    float4 xv = xr[k4];
    acc = fmaf(xv.x, w[(k4 * 4 + 0) * 32 + c], acc);
    acc = fmaf(xv.y, w[(k4 * 4 + 1) * 32 + c], acc);
    acc = fmaf(xv.z, w[(k4 * 4 + 2) * 32 + c], acc);
    acc = fmaf(xv.w, w[(k4 * 4 + 3) * 32 + c], acc);
  }
  hWs[gid] = dinv[r] * acc;
}

// hWs = dinv[r] * (relu(h) @ W2)   (h: [N,32] pre-ReLU, W2: [32,32])
__global__ __launch_bounds__(256) void k_gemm2(
    const float* __restrict__ h, const float* __restrict__ W2,
    const float* __restrict__ dinv, float* __restrict__ hWs, int N) {
  __shared__ float w[32 * 32];
  for (int i = threadIdx.x; i < 32 * 32; i += 256) w[i] = W2[i];
  __syncthreads();
  int gid = blockIdx.x * 256 + threadIdx.x;
  int r = gid >> 5, c = gid & 31;
  if (r >= N) return;
  const float4* hr = (const float4*)(h + (size_t)r * 32);
  float acc = 0.f;
#pragma unroll
  for (int k4 = 0; k4 < 8; ++k4) {
    float4 v = hr[k4];
    acc = fmaf(fmaxf(v.x, 0.f), w[(k4 * 4 + 0) * 32 + c], acc);
    acc = fmaf(fmaxf(v.y, 0.f), w[(k4 * 4 + 1) * 32 + c], acc);
    acc = fmaf(fmaxf(v.z, 0.f), w[(k4 * 4 + 2) * 32 + c], acc);
    acc = fmaf(fmaxf(v.w, 0.f), w[(k4 * 4 + 3) * 32 + c], acc);
  }
  hWs[gid] = dinv[r] * acc;
}

// agg[i,c] = b[c] + dinv[i]*(hWs[i,c] + sum_j hWs[s_j,c])
// 32 lanes per node; lane = feature column. 4-way unrolled edge loop.
__global__ __launch_bounds__(256) void k_gather(
    const int* __restrict__ esrc, const int* __restrict__ rowptr,
    const float* __restrict__ dinv, const float* __restrict__ hWs,
    const float* __restrict__ bias, float* __restrict__ agg, int N) {
  int gid = blockIdx.x * 256 + threadIdx.x;
  int i = gid >> 5, c = gid & 31;
  if (i >= N) return;
  float acc = hWs[(size_t)i * 32 + c];
  int beg = rowptr[i], end = rowptr[i + 1];
  int j = beg;
  for (; j + 3 < end; j += 4) {
    int s0 = esrc[j], s1 = esrc[j + 1], s2 = esrc[j + 2], s3 = esrc[j + 3];
    float v0 = hWs[(size_t)s0 * 32 + c];
    float v1 = hWs[(size_t)s1 * 32 + c];
    float v2 = hWs[(size_t)s2 * 32 + c];
    float v3 = hWs[(size_t)s3 * 32 + c];
    acc += (v0 + v1) + (v2 + v3);
  }
  for (; j < end; ++j) acc += hWs[(size_t)esrc[j] * 32 + c];
  agg[(size_t)i * 32 + c] = fmaf(dinv[i], acc, bias[c]);
}

// layer-2 gather + fused score head:
// scores[1+i] = sum_c relu(b[c]+dinv[i]*(...)) * Wh[c] + bh ; scores[0] = cash
__global__ __launch_bounds__(256) void k_gather_score(
    const int* __restrict__ esrc, const int* __restrict__ rowptr,
    const float* __restrict__ dinv, const float* __restrict__ hWs,
    const float* __restrict__ bias, const float* __restrict__ Wh,
    const float* __restrict__ bh, const float* __restrict__ cash,
    float* __restrict__ scores, int N) {
  int gid = blockIdx.x * 256 + threadIdx.x;
  if (gid == 0) scores[0] = cash[0];
  int i = gid >> 5, c = gid & 31;
  if (i >= N) return;
  float acc = hWs[(size_t)i * 32 + c];
  int beg = rowptr[i], end = rowptr[i + 1];
  int j = beg;
  for (; j + 3 < end; j += 4) {
    int s0 = esrc[j], s1 = esrc[j + 1], s2 = esrc[j + 2], s3 = esrc[j + 3];
    float v0 = hWs[(size_t)s0 * 32 + c];
    float v1 = hWs[(size_t)s1 * 32 + c];
    float v2 = hWs[(size_t)s2 * 32 + c];
    float v3 = hWs[(size_t)s3 * 32 + c];
    acc += (v0 + v1) + (v2 + v3);
  }
  for (; j < end; ++j) acc += hWs[(size_t)esrc[j] * 32 + c];
  float val = fmaf(dinv[i], acc, bias[c]);
  float t = fmaxf(val, 0.f) * Wh[c];
#pragma unroll
  for (int m = 16; m >= 1; m >>= 1) t += __shfl_xor(t, m, 32);
  if (c == 0) scores[1 + i] = t + bh[0];
}

// --- softmax over N+1 scores ---
__global__ void k_red_max(const float* __restrict__ s, int n, float* __restrict__ part) {
  float m = -3.4e38f;
  for (int i = blockIdx.x * blockDim.x + threadIdx.x; i < n; i += gridDim.x * blockDim.x)
    m = fmaxf(m, s[i]);
  __shared__ float sm[256];
  sm[threadIdx.x] = m;
  __syncthreads();
  for (int o = 128; o > 0; o >>= 1) {
    if (threadIdx.x < o) sm[threadIdx.x] = fmaxf(sm[threadIdx.x], sm[threadIdx.x + o]);
    __syncthreads();
  }
  if (threadIdx.x == 0) part[blockIdx.x] = sm[0];
}

__global__ void k_red_sumexp(const float* __restrict__ s, int n,
                             const float* __restrict__ mptr, float* __restrict__ part) {
  float m = *mptr;
  float acc = 0.f;
  for (int i = blockIdx.x * blockDim.x + threadIdx.x; i < n; i += gridDim.x * blockDim.x)
    acc += expf(s[i] - m);
  __shared__ float sm[256];
  sm[threadIdx.x] = acc;
  __syncthreads();
  for (int o = 128; o > 0; o >>= 1) {
    if (threadIdx.x < o) sm[threadIdx.x] += sm[threadIdx.x + o];
    __syncthreads();
  }
  if (threadIdx.x == 0) part[blockIdx.x] = sm[0];
}

__global__ void k_red_sum(const float* __restrict__ s, int n, float* __restrict__ outp) {
  float acc = 0.f;
  for (int i = threadIdx.x; i < n; i += blockDim.x) acc += s[i];
  __shared__ float sm[256];
  sm[threadIdx.x] = acc;
  __syncthreads();
  for (int o = 128; o > 0; o >>= 1) {
    if (threadIdx.x < o) sm[threadIdx.x] += sm[threadIdx.x + o];
    __syncthreads();
  }
  if (threadIdx.x == 0) *outp = sm[0];
}

__global__ void k_softmax_out(const float* __restrict__ s, int n,
                              const float* __restrict__ finals, float* __restrict__ out) {
  int i = blockIdx.x * 256 + threadIdx.x;
  if (i < n) out[i] = expf(s[i] - finals[0]) / finals[1];
}

extern "C" void kernel_launch(void* const* d_in, const int* in_sizes, int n_in,
                              void* d_out, int out_size, void* d_ws, size_t ws_size,
                              hipStream_t stream) {
  const float* x    = (const float*)d_in[0];
  const int*   ei   = (const int*)d_in[1];
  const float* W1   = (const float*)d_in[2];
  const float* b1   = (const float*)d_in[3];
  const float* W2   = (const float*)d_in[4];
  const float* b2   = (const float*)d_in[5];
  const float* Wh   = (const float*)d_in[6];
  const float* bh   = (const float*)d_in[7];
  const float* cash = (const float*)d_in[8];

  const int N = in_sizes[0] / 128;
  const int E = in_sizes[1] / 2;
  const int* src = ei;
  const int* dst = ei + E;
  const int NB = cdiv(N, CH);  // scan blocks (98 for N=100000, <=256)

  char* p = (char*)d_ws;
  float* dinv   = (float*)p; p += sizeof(float) * N;
  float* hWs    = (float*)p; p += sizeof(float) * (size_t)N * 32;
  float* agg    = (float*)p; p += sizeof(float) * (size_t)N * 32;
  float* scores = (float*)p; p += sizeof(float) * (N + 1);
  float* part   = (float*)p; p += sizeof(float) * 256;
  float* finals = (float*)p; p += sizeof(float) * 4;
  int* cnt    = (int*)p; p += sizeof(int) * (size_t)N * PAD;  // line-padded
  int* rowptr = (int*)p; p += sizeof(int) * (N + 1);
  int* bsum   = (int*)p; p += sizeof(int) * 256;
  int* myidx  = (int*)p; p += sizeof(int) * (size_t)E;
  int* esrc   = (int*)p; p += sizeof(int) * (size_t)E;
  float* out = (float*)d_out;
  const int n = N + 1;

  // --- CSR build (shared by both layers) ---
  hipMemsetAsync(cnt, 0, sizeof(int) * (size_t)N * PAD, stream);
  k_hist<<<cdiv(E, 256), 256, 0, stream>>>(dst, cnt, myidx, E);
  k_scan1<<<NB, 256, 0, stream>>>(cnt, N, rowptr, bsum, dinv);
  k_scan2<<<1, 256, 0, stream>>>(bsum, NB);
  k_scan3<<<cdiv(N, 256), 256, 0, stream>>>(rowptr, bsum, N, E);
  k_fill<<<cdiv(E, 256), 256, 0, stream>>>(src, dst, rowptr, myidx, esrc, E);

  // --- layer 1 ---
  k_gemm1<<<cdiv((long)N * 32, 256), 256, 0, stream>>>(x, W1, dinv, hWs, N);
  k_gather<<<cdiv((long)N * 32, 256), 256, 0, stream>>>(esrc, rowptr, dinv, hWs, b1, agg, N);

  // --- layer 2 with fused score head ---
  k_gemm2<<<cdiv((long)N * 32, 256), 256, 0, stream>>>(agg, W2, dinv, hWs, N);
  k_gather_score<<<cdiv((long)N * 32, 256), 256, 0, stream>>>(
      esrc, rowptr, dinv, hWs, b2, Wh, bh, cash, scores, N);

  // --- softmax ---
  k_red_max<<<256, 256, 0, stream>>>(scores, n, part);
  k_red_max<<<1, 256, 0, stream>>>(part, 256, finals);
  k_red_sumexp<<<256, 256, 0, stream>>>(scores, n, finals, part);
  k_red_sum<<<1, 256, 0, stream>>>(part, 256, finals + 1);
  k_softmax_out<<<cdiv(n, 256), 256, 0, stream>>>(scores, n, finals, out);
}

// Round 9
// 346.548 us; speedup vs baseline: 4.5108x; 1.1976x over previous
//
#include <hip/hip_runtime.h>
#include <math.h>

// GCN forward: bucket-sort CSR build + node-parallel gather.
// Measured models (R4-R8):
//   - each device-scope global atomic ~= 35B fabric traffic + ~41ns throughput,
//     INVARIANT to layout/locality (R4 vs R5 vs R8-padded all WRITE=112MB).
//     => only reducing atomic COUNT helps: k_bin uses ~306k vs hist's 3.2M.
//   - gather must be node-parallel (3.2M lanes; R7's 782-block version died).
//   - scattered non-atomic stores confined to block-private contiguous runs
//     are L2-absorbed (R4 k_fill); k_place writes 16KB runs per block.
// Pipeline: k_bin (LDS-hist binning, packed (d&127)<<17|src) -> k_bukscan
//   (782-entry scan -> bbase) -> k_place (per-bucket LDS count+scan ->
//   rowptr/dinv/esrc, zero global atomics) -> per layer GEMM (hWs =
//   dinv*feat@W) + gather (acc += hWs[s], one coalesced 128B req/edge);
//   layer-2 gather fuses score head; online-softmax in 3 kernels.

static inline int cdiv(long a, int b) { return (int)((a + (long)b - 1) / b); }

#define EPB 8192      // edges per k_bin block
#define BUKMAX 1024   // max buckets (N <= 131072)
#define CAP 4608      // per-bucket capacity; mean 4096, 8-sigma pad

// --- binning: LDS hist -> one reservation atomic per (block,bucket) -> fill runs
__global__ __launch_bounds__(256) void k_bin(const int* __restrict__ src,
                                             const int* __restrict__ dst,
                                             unsigned* __restrict__ gcur,
                                             unsigned* __restrict__ ebuf,
                                             int E, int nbuk) {
  __shared__ unsigned lhist[BUKMAX];
  __shared__ unsigned lcur[BUKMAX];
  int tid = threadIdx.x;
  for (int i = tid; i < nbuk; i += 256) lhist[i] = 0;
  __syncthreads();
  int e0 = blockIdx.x * EPB, e1 = min(e0 + EPB, E);
  for (int e = e0 + tid; e < e1; e += 256)
    atomicAdd(&lhist[__builtin_nontemporal_load(&dst[e]) >> 7], 1u);
  __syncthreads();
  for (int b = tid; b < nbuk; b += 256) {
    unsigned nn = lhist[b];
    lcur[b] = nn ? atomicAdd(&gcur[b], nn) : 0u;  // run reservation
  }
  __syncthreads();
  for (int e = e0 + tid; e < e1; e += 256) {
    int d = __builtin_nontemporal_load(&dst[e]);
    int s = __builtin_nontemporal_load(&src[e]);
    int b = d >> 7;
    unsigned off = atomicAdd(&lcur[b], 1u);  // LDS cursor (starts at reservation)
    if (off < CAP)  // overflow guard, P ~ 1e-11
      ebuf[(size_t)b * CAP + off] = ((unsigned)(d & 127) << 17) | (unsigned)s;
  }
}

// --- exclusive scan of bucket counts (one block; nbuk <= 1024)
__global__ __launch_bounds__(1024) void k_bukscan(const unsigned* __restrict__ gcur,
                                                  unsigned* __restrict__ bbase,
                                                  int* __restrict__ rowptr,
                                                  int nbuk, int N) {
  __shared__ unsigned sm[1024];
  int t = threadIdx.x;
  unsigned v = (t < nbuk) ? min(gcur[t], (unsigned)CAP) : 0u;
  sm[t] = v;
  __syncthreads();
  for (int o = 1; o < 1024; o <<= 1) {
    unsigned add = (t >= o) ? sm[t - o] : 0u;
    __syncthreads();
    sm[t] += add;
    __syncthreads();
  }
  if (t < nbuk) bbase[t] = sm[t] - v;  // exclusive
  if (t == 1023) rowptr[N] = (int)sm[1023];
}

// --- per-bucket: LDS node-count + scan -> rowptr/dinv; place run into esrc.
// Zero global atomics; esrc writes confined to this block's 16KB region.
__global__ __launch_bounds__(256) void k_place(const unsigned* __restrict__ gcur,
                                               const unsigned* __restrict__ ebuf,
                                               const unsigned* __restrict__ bbase,
                                               int* __restrict__ rowptr,
                                               float* __restrict__ dinv,
                                               int* __restrict__ esrc, int N) {
  __shared__ unsigned lcnt[128];
  __shared__ unsigned lofs[128];
  int b = blockIdx.x, tid = threadIdx.x;
  if (tid < 128) lcnt[tid] = 0;
  __syncthreads();
  int cnt = min((int)gcur[b], CAP);
  const unsigned* eb = ebuf + (size_t)b * CAP;
  for (int j = tid; j < cnt; j += 256) atomicAdd(&lcnt[eb[j] >> 17], 1u);
  __syncthreads();
  unsigned myc = (tid < 128) ? lcnt[tid] : 0u;
  if (tid < 128) lofs[tid] = myc;
  __syncthreads();
  for (int o = 1; o < 128; o <<= 1) {  // inclusive scan over 128
    unsigned add = (tid < 128 && tid >= o) ? lofs[tid - o] : 0u;
    __syncthreads();
    if (tid < 128) lofs[tid] += add;
    __syncthreads();
  }
  unsigned base = bbase[b];
  if (tid < 128) {
    unsigned ex = lofs[tid] - myc;  // exclusive
    int node = (b << 7) + tid;
    if (node < N) {
      rowptr[node] = (int)(base + ex);
      dinv[node] = rsqrtf((float)myc + 1.0f);  // deg = cnt + self-loop
    }
    lofs[tid] = ex;  // reuse as cursor
  }
  __syncthreads();
  for (int j = tid; j < cnt; j += 256) {
    unsigned p = eb[j];
    unsigned r = atomicAdd(&lofs[p >> 17], 1u);  // LDS atomic
    esrc[base + r] = (int)(p & 0x1FFFF);
  }
}

// hWs = dinv[r] * (x @ W1)   (x: [N,128], W1: [128,32])
__global__ __launch_bounds__(256) void k_gemm1(
    const float* __restrict__ x, const float* __restrict__ W1,
    const float* __restrict__ dinv, float* __restrict__ hWs, int N) {
  __shared__ float w[128 * 32];
  for (int i = threadIdx.x; i < 128 * 32; i += 256) w[i] = W1[i];
  __syncthreads();
  int gid = blockIdx.x * 256 + threadIdx.x;
  int r = gid >> 5, c = gid & 31;
  if (r >= N) return;
  const float4* xr = (const float4*)(x + (size_t)r * 128);
  float acc = 0.f;
#pragma unroll
  for (int k4 = 0; k4 < 32; ++k4) {
    float4 xv = xr[k4];
    acc = fmaf(xv.x, w[(k4 * 4 + 0) * 32 + c], acc);
    acc = fmaf(xv.y, w[(k4 * 4 + 1) * 32 + c], acc);
    acc = fmaf(xv.z, w[(k4 * 4 + 2) * 32 + c], acc);
    acc = fmaf(xv.w, w[(k4 * 4 + 3) * 32 + c], acc);
  }
  hWs[gid] = dinv[r] * acc;
}

// hWs = dinv[r] * (relu(h) @ W2)   (h: [N,32] pre-ReLU, W2: [32,32])
__global__ __launch_bounds__(256) void k_gemm2(
    const float* __restrict__ h, const float* __restrict__ W2,
    const float* __restrict__ dinv, float* __restrict__ hWs, int N) {
  __shared__ float w[32 * 32];
  for (int i = threadIdx.x; i < 32 * 32; i += 256) w[i] = W2[i];
  __syncthreads();
  int gid = blockIdx.x * 256 + threadIdx.x;
  int r = gid >> 5, c = gid & 31;
  if (r >= N) return;
  const float4* hr = (const float4*)(h + (size_t)r * 32);
  float acc = 0.f;
#pragma unroll
  for (int k4 = 0; k4 < 8; ++k4) {
    float4 v = hr[k4];
    acc = fmaf(fmaxf(v.x, 0.f), w[(k4 * 4 + 0) * 32 + c], acc);
    acc = fmaf(fmaxf(v.y, 0.f), w[(k4 * 4 + 1) * 32 + c], acc);
    acc = fmaf(fmaxf(v.z, 0.f), w[(k4 * 4 + 2) * 32 + c], acc);
    acc = fmaf(fmaxf(v.w, 0.f), w[(k4 * 4 + 3) * 32 + c], acc);
  }
  hWs[gid] = dinv[r] * acc;
}

// agg[i,c] = b[c] + dinv[i]*(hWs[i,c] + sum_j hWs[s_j,c]); 32 lanes/node.
__global__ __launch_bounds__(256) void k_gather(
    const int* __restrict__ esrc, const int* __restrict__ rowptr,
    const float* __restrict__ dinv, const float* __restrict__ hWs,
    const float* __restrict__ bias, float* __restrict__ agg, int N) {
  int gid = blockIdx.x * 256 + threadIdx.x;
  int i = gid >> 5, c = gid & 31;
  if (i >= N) return;
  float acc = hWs[(size_t)i * 32 + c];
  int beg = rowptr[i], end = rowptr[i + 1];
  int j = beg;
  for (; j + 3 < end; j += 4) {
    int s0 = esrc[j], s1 = esrc[j + 1], s2 = esrc[j + 2], s3 = esrc[j + 3];
    float v0 = hWs[(size_t)s0 * 32 + c];
    float v1 = hWs[(size_t)s1 * 32 + c];
    float v2 = hWs[(size_t)s2 * 32 + c];
    float v3 = hWs[(size_t)s3 * 32 + c];
    acc += (v0 + v1) + (v2 + v3);
  }
  for (; j < end; ++j) acc += hWs[(size_t)esrc[j] * 32 + c];
  agg[(size_t)i * 32 + c] = fmaf(dinv[i], acc, bias[c]);
}

// layer-2 gather + fused score head (32-lane shfl reduce)
__global__ __launch_bounds__(256) void k_gather_score(
    const int* __restrict__ esrc, const int* __restrict__ rowptr,
    const float* __restrict__ dinv, const float* __restrict__ hWs,
    const float* __restrict__ bias, const float* __restrict__ Wh,
    const float* __restrict__ bh, const float* __restrict__ cash,
    float* __restrict__ scores, int N) {
  int gid = blockIdx.x * 256 + threadIdx.x;
  if (gid == 0) scores[0] = cash[0];
  int i = gid >> 5, c = gid & 31;
  if (i >= N) return;
  float acc = hWs[(size_t)i * 32 + c];
  int beg = rowptr[i], end = rowptr[i + 1];
  int j = beg;
  for (; j + 3 < end; j += 4) {
    int s0 = esrc[j], s1 = esrc[j + 1], s2 = esrc[j + 2], s3 = esrc[j + 3];
    float v0 = hWs[(size_t)s0 * 32 + c];
    float v1 = hWs[(size_t)s1 * 32 + c];
    float v2 = hWs[(size_t)s2 * 32 + c];
    float v3 = hWs[(size_t)s3 * 32 + c];
    acc += (v0 + v1) + (v2 + v3);
  }
  for (; j < end; ++j) acc += hWs[(size_t)esrc[j] * 32 + c];
  float val = fmaf(dinv[i], acc, bias[c]);
  float t = fmaxf(val, 0.f) * Wh[c];
#pragma unroll
  for (int m = 16; m >= 1; m >>= 1) t += __shfl_xor(t, m, 32);
  if (c == 0) scores[1 + i] = t + bh[0];
}

// --- online softmax: per-block (max, sumexp) partials ---
__global__ __launch_bounds__(256) void k_sm_part(const float* __restrict__ s, int n,
                                                 float2* __restrict__ part) {
  float m = -3.4e38f, sum = 0.f;
  for (int i = blockIdx.x * 256 + threadIdx.x; i < n; i += 256 * 256) {
    float x = s[i];
    if (x > m) { sum = sum * expf(m - x) + 1.f; m = x; }
    else sum += expf(x - m);
  }
  __shared__ float sm_m[256], sm_s[256];
  sm_m[threadIdx.x] = m; sm_s[threadIdx.x] = sum;
  __syncthreads();
  for (int o = 128; o > 0; o >>= 1) {
    if (threadIdx.x < o) {
      float m1 = sm_m[threadIdx.x], s1 = sm_s[threadIdx.x];
      float m2 = sm_m[threadIdx.x + o], s2 = sm_s[threadIdx.x + o];
      float M = fmaxf(m1, m2);
      sm_s[threadIdx.x] = s1 * expf(m1 - M) + s2 * expf(m2 - M);
      sm_m[threadIdx.x] = M;
    }
    __syncthreads();
  }
  if (threadIdx.x == 0) part[blockIdx.x] = make_float2(sm_m[0], sm_s[0]);
}

__global__ __launch_bounds__(256) void k_sm_fin(const float2* __restrict__ part,
                                                float* __restrict__ finals) {
  __shared__ float sm_m[256], sm_s[256];
  float2 p = part[threadIdx.x];
  sm_m[threadIdx.x] = p.x; sm_s[threadIdx.x] = p.y;
  __syncthreads();
  for (int o = 128; o > 0; o >>= 1) {
    if (threadIdx.x < o) {
      float m1 = sm_m[threadIdx.x], s1 = sm_s[threadIdx.x];
      float m2 = sm_m[threadIdx.x + o], s2 = sm_s[threadIdx.x + o];
      float M = fmaxf(m1, m2);
      sm_s[threadIdx.x] = s1 * expf(m1 - M) + s2 * expf(m2 - M);
      sm_m[threadIdx.x] = M;
    }
    __syncthreads();
  }
  if (threadIdx.x == 0) { finals[0] = sm_m[0]; finals[1] = sm_s[0]; }
}

__global__ void k_sm_out(const float* __restrict__ s, int n,
                         const float* __restrict__ finals, float* __restrict__ out) {
  int i = blockIdx.x * 256 + threadIdx.x;
  if (i < n) out[i] = expf(s[i] - finals[0]) / finals[1];
}

extern "C" void kernel_launch(void* const* d_in, const int* in_sizes, int n_in,
                              void* d_out, int out_size, void* d_ws, size_t ws_size,
                              hipStream_t stream) {
  const float* x    = (const float*)d_in[0];
  const int*   ei   = (const int*)d_in[1];
  const float* W1   = (const float*)d_in[2];
  const float* b1   = (const float*)d_in[3];
  const float* W2   = (const float*)d_in[4];
  const float* b2   = (const float*)d_in[5];
  const float* Wh   = (const float*)d_in[6];
  const float* bh   = (const float*)d_in[7];
  const float* cash = (const float*)d_in[8];

  const int N = in_sizes[0] / 128;
  const int E = in_sizes[1] / 2;
  const int* src = ei;
  const int* dst = ei + E;
  const int nbuk = cdiv(N, 128);  // 782 for N=100000 (<= BUKMAX)

  char* p = (char*)d_ws;
  float* dinv   = (float*)p; p += sizeof(float) * N;
  float* hWs    = (float*)p; p += sizeof(float) * (size_t)N * 32;
  float* agg    = (float*)p; p += sizeof(float) * (size_t)N * 32;
  float* scores = (float*)p; p += sizeof(float) * (N + 1);
  float2* part  = (float2*)p; p += sizeof(float2) * 256;
  float* finals = (float*)p; p += sizeof(float) * 4;
  unsigned* gcur  = (unsigned*)p; p += sizeof(unsigned) * BUKMAX;
  unsigned* bbase = (unsigned*)p; p += sizeof(unsigned) * BUKMAX;
  int* rowptr = (int*)p; p += sizeof(int) * (N + 1);
  unsigned* ebuf = (unsigned*)p; p += sizeof(unsigned) * (size_t)nbuk * CAP;
  int* esrc   = (int*)p; p += sizeof(int) * (size_t)E;
  float* out = (float*)d_out;
  const int n = N + 1;

  // --- CSR build (bucket sort; shared by both layers) ---
  hipMemsetAsync(gcur, 0, sizeof(unsigned) * BUKMAX, stream);
  k_bin<<<cdiv(E, EPB), 256, 0, stream>>>(src, dst, gcur, ebuf, E, nbuk);
  k_bukscan<<<1, 1024, 0, stream>>>(gcur, bbase, rowptr, nbuk, N);
  k_place<<<nbuk, 256, 0, stream>>>(gcur, ebuf, bbase, rowptr, dinv, esrc, N);

  // --- layer 1 ---
  k_gemm1<<<cdiv((long)N * 32, 256), 256, 0, stream>>>(x, W1, dinv, hWs, N);
  k_gather<<<cdiv((long)N * 32, 256), 256, 0, stream>>>(esrc, rowptr, dinv, hWs, b1, agg, N);

  // --- layer 2 with fused score head ---
  k_gemm2<<<cdiv((long)N * 32, 256), 256, 0, stream>>>(agg, W2, dinv, hWs, N);
  k_gather_score<<<cdiv((long)N * 32, 256), 256, 0, stream>>>(
      esrc, rowptr, dinv, hWs, b2, Wh, bh, cash, scores, N);

  // --- online softmax (3 kernels) ---
  k_sm_part<<<256, 256, 0, stream>>>(scores, n, part);
  k_sm_fin<<<1, 256, 0, stream>>>(part, finals);
  k_sm_out<<<cdiv(n, 256), 256, 0, stream>>>(scores, n, finals, out);
}

// Round 11
// 346.041 us; speedup vs baseline: 4.5174x; 1.0015x over previous
//
#include <hip/hip_runtime.h>
#include <math.h>

// GCN forward: bucket-sort CSR build + node-parallel gather (bf16 messages).
// Measured models (R4-R9):
//   - each device-scope global atomic ~= 35B fabric traffic + ~41ns chip
//     throughput, INVARIANT to layout/locality. Only atomic COUNT matters.
//   - k_bin R9: 391 blocks -> 14.7% occupancy, latency-bound. This round:
//     EPB=4096 (782 blocks) + vectorized edge reads (ext_vector int4 --
//     HIP's int4 class is rejected by __builtin_nontemporal_load).
//   - gathers dominated by random 128B hWs row reads (12.8MB table > 4MB XCD
//     L2). This round: hWs stored bf16 (f32 accumulate) -> 64B rows, 6.4MB
//     table -> higher L2 hit + half bytes. Error budget ~1.4e-8 << 2.12e-7.
// Pipeline: k_bin (LDS-hist binning, packed (d&127)<<17|src) -> k_bukscan ->
//   k_place (per-bucket LDS count+scan -> rowptr/dinv/esrc, no global atomics)
//   -> per layer GEMM (hWs = bf16(dinv*feat@W)) + gather; layer-2 gather fuses
//   score head; online-softmax in 3 kernels.

static inline int cdiv(long a, int b) { return (int)((a + (long)b - 1) / b); }

#define EPB 4096      // edges per k_bin block (782 blocks @ E=3.2M)
#define BUKMAX 1024   // max buckets (N <= 131072)
#define CAP 4608      // per-bucket capacity; mean 4096, 8-sigma pad

typedef unsigned short u16;
typedef int iv4 __attribute__((ext_vector_type(4)));  // clang vector: ok for nontemporal builtin

__device__ __forceinline__ u16 f2bf(float f) {  // RNE f32->bf16
  unsigned u = __float_as_uint(f);
  return (u16)((u + 0x7FFFu + ((u >> 16) & 1u)) >> 16);
}
__device__ __forceinline__ float bf2f(u16 h) {
  return __uint_as_float(((unsigned)h) << 16);
}

// --- binning: LDS hist -> one reservation atomic per (block,bucket) -> fill runs
__global__ __launch_bounds__(256) void k_bin(const int* __restrict__ src,
                                             const int* __restrict__ dst,
                                             unsigned* __restrict__ gcur,
                                             unsigned* __restrict__ ebuf,
                                             int E, int nbuk) {
  __shared__ unsigned lhist[BUKMAX];
  __shared__ unsigned lcur[BUKMAX];
  int tid = threadIdx.x;
  for (int i = tid; i < nbuk; i += 256) lhist[i] = 0;
  __syncthreads();
  int e0 = blockIdx.x * EPB, e1 = min(e0 + EPB, E);
  int nvec = (e1 - e0) >> 10;  // 1024-edge chunks (256 thr x 4)
  for (int k = 0; k < nvec; ++k) {
    iv4 d4 = __builtin_nontemporal_load((const iv4*)(dst + e0 + (k << 10) + tid * 4));
    atomicAdd(&lhist[d4.x >> 7], 1u);
    atomicAdd(&lhist[d4.y >> 7], 1u);
    atomicAdd(&lhist[d4.z >> 7], 1u);
    atomicAdd(&lhist[d4.w >> 7], 1u);
  }
  for (int e = e0 + (nvec << 10) + tid; e < e1; e += 256)
    atomicAdd(&lhist[__builtin_nontemporal_load(&dst[e]) >> 7], 1u);
  __syncthreads();
  for (int b = tid; b < nbuk; b += 256) {
    unsigned nn = lhist[b];
    lcur[b] = nn ? atomicAdd(&gcur[b], nn) : 0u;  // run reservation
  }
  __syncthreads();
  for (int k = 0; k < nvec; ++k) {
    int base = e0 + (k << 10) + tid * 4;
    iv4 d4 = __builtin_nontemporal_load((const iv4*)(dst + base));
    iv4 s4 = __builtin_nontemporal_load((const iv4*)(src + base));
#define PUT(dd, ss)                                              \
    {                                                            \
      unsigned off = atomicAdd(&lcur[(dd) >> 7], 1u);            \
      if (off < CAP)                                             \
        ebuf[(size_t)((dd) >> 7) * CAP + off] =                  \
            ((unsigned)((dd) & 127) << 17) | (unsigned)(ss);     \
    }
    PUT(d4.x, s4.x) PUT(d4.y, s4.y) PUT(d4.z, s4.z) PUT(d4.w, s4.w)
  }
  for (int e = e0 + (nvec << 10) + tid; e < e1; e += 256) {
    int d = __builtin_nontemporal_load(&dst[e]);
    int s = __builtin_nontemporal_load(&src[e]);
    PUT(d, s)
  }
#undef PUT
}

// --- exclusive scan of bucket counts (one block; nbuk <= 1024)
__global__ __launch_bounds__(1024) void k_bukscan(const unsigned* __restrict__ gcur,
                                                  unsigned* __restrict__ bbase,
                                                  int* __restrict__ rowptr,
                                                  int nbuk, int N) {
  __shared__ unsigned sm[1024];
  int t = threadIdx.x;
  unsigned v = (t < nbuk) ? min(gcur[t], (unsigned)CAP) : 0u;
  sm[t] = v;
  __syncthreads();
  for (int o = 1; o < 1024; o <<= 1) {
    unsigned add = (t >= o) ? sm[t - o] : 0u;
    __syncthreads();
    sm[t] += add;
    __syncthreads();
  }
  if (t < nbuk) bbase[t] = sm[t] - v;  // exclusive
  if (t == 1023) rowptr[N] = (int)sm[1023];
}

// --- per-bucket: LDS node-count + scan -> rowptr/dinv; place run into esrc.
__global__ __launch_bounds__(256) void k_place(const unsigned* __restrict__ gcur,
                                               const unsigned* __restrict__ ebuf,
                                               const unsigned* __restrict__ bbase,
                                               int* __restrict__ rowptr,
                                               float* __restrict__ dinv,
                                               int* __restrict__ esrc, int N) {
  __shared__ unsigned lcnt[128];
  __shared__ unsigned lofs[128];
  int b = blockIdx.x, tid = threadIdx.x;
  if (tid < 128) lcnt[tid] = 0;
  __syncthreads();
  int cnt = min((int)gcur[b], CAP);
  const unsigned* eb = ebuf + (size_t)b * CAP;
  for (int j = tid; j < cnt; j += 256) atomicAdd(&lcnt[eb[j] >> 17], 1u);
  __syncthreads();
  unsigned myc = (tid < 128) ? lcnt[tid] : 0u;
  if (tid < 128) lofs[tid] = myc;
  __syncthreads();
  for (int o = 1; o < 128; o <<= 1) {
    unsigned add = (tid < 128 && tid >= o) ? lofs[tid - o] : 0u;
    __syncthreads();
    if (tid < 128) lofs[tid] += add;
    __syncthreads();
  }
  unsigned base = bbase[b];
  if (tid < 128) {
    unsigned ex = lofs[tid] - myc;
    int node = (b << 7) + tid;
    if (node < N) {
      rowptr[node] = (int)(base + ex);
      dinv[node] = rsqrtf((float)myc + 1.0f);  // deg = cnt + self-loop
    }
    lofs[tid] = ex;  // reuse as cursor
  }
  __syncthreads();
  for (int j = tid; j < cnt; j += 256) {
    unsigned p = eb[j];
    unsigned r = atomicAdd(&lofs[p >> 17], 1u);  // LDS atomic
    esrc[base + r] = (int)(p & 0x1FFFF);
  }
}

// hWs = bf16(dinv[r] * (x @ W1))   (x: [N,128], W1: [128,32])
__global__ __launch_bounds__(256) void k_gemm1(
    const float* __restrict__ x, const float* __restrict__ W1,
    const float* __restrict__ dinv, u16* __restrict__ hWs, int N) {
  __shared__ float w[128 * 32];
  for (int i = threadIdx.x; i < 128 * 32; i += 256) w[i] = W1[i];
  __syncthreads();
  int gid = blockIdx.x * 256 + threadIdx.x;
  int r = gid >> 5, c = gid & 31;
  if (r >= N) return;
  const float4* xr = (const float4*)(x + (size_t)r * 128);
  float acc = 0.f;
#pragma unroll
  for (int k4 = 0; k4 < 32; ++k4) {
    float4 xv = xr[k4];
    acc = fmaf(xv.x, w[(k4 * 4 + 0) * 32 + c], acc);
    acc = fmaf(xv.y, w[(k4 * 4 + 1) * 32 + c], acc);
    acc = fmaf(xv.z, w[(k4 * 4 + 2) * 32 + c], acc);
    acc = fmaf(xv.w, w[(k4 * 4 + 3) * 32 + c], acc);
  }
  hWs[gid] = f2bf(dinv[r] * acc);
}

// hWs = bf16(dinv[r] * (relu(h) @ W2))   (h: [N,32] pre-ReLU f32, W2: [32,32])
__global__ __launch_bounds__(256) void k_gemm2(
    const float* __restrict__ h, const float* __restrict__ W2,
    const float* __restrict__ dinv, u16* __restrict__ hWs, int N) {
  __shared__ float w[32 * 32];
  for (int i = threadIdx.x; i < 32 * 32; i += 256) w[i] = W2[i];
  __syncthreads();
  int gid = blockIdx.x * 256 + threadIdx.x;
  int r = gid >> 5, c = gid & 31;
  if (r >= N) return;
  const float4* hr = (const float4*)(h + (size_t)r * 32);
  float acc = 0.f;
#pragma unroll
  for (int k4 = 0; k4 < 8; ++k4) {
    float4 v = hr[k4];
    acc = fmaf(fmaxf(v.x, 0.f), w[(k4 * 4 + 0) * 32 + c], acc);
    acc = fmaf(fmaxf(v.y, 0.f), w[(k4 * 4 + 1) * 32 + c], acc);
    acc = fmaf(fmaxf(v.z, 0.f), w[(k4 * 4 + 2) * 32 + c], acc);
    acc = fmaf(fmaxf(v.w, 0.f), w[(k4 * 4 + 3) * 32 + c], acc);
  }
  hWs[gid] = f2bf(dinv[r] * acc);
}

// agg[i,c] = b[c] + dinv[i]*(hWs[i,c] + sum_j hWs[s_j,c]); 32 lanes/node.
// bf16 rows: one coalesced 64B request per edge.
__global__ __launch_bounds__(256) void k_gather(
    const int* __restrict__ esrc, const int* __restrict__ rowptr,
    const float* __restrict__ dinv, const u16* __restrict__ hWs,
    const float* __restrict__ bias, float* __restrict__ agg, int N) {
  int gid = blockIdx.x * 256 + threadIdx.x;
  int i = gid >> 5, c = gid & 31;
  if (i >= N) return;
  float acc = bf2f(hWs[(size_t)i * 32 + c]);
  int beg = rowptr[i], end = rowptr[i + 1];
  int j = beg;
  for (; j + 3 < end; j += 4) {
    int s0 = esrc[j], s1 = esrc[j + 1], s2 = esrc[j + 2], s3 = esrc[j + 3];
    float v0 = bf2f(hWs[(size_t)s0 * 32 + c]);
    float v1 = bf2f(hWs[(size_t)s1 * 32 + c]);
    float v2 = bf2f(hWs[(size_t)s2 * 32 + c]);
    float v3 = bf2f(hWs[(size_t)s3 * 32 + c]);
    acc += (v0 + v1) + (v2 + v3);
  }
  for (; j < end; ++j) acc += bf2f(hWs[(size_t)esrc[j] * 32 + c]);
  agg[(size_t)i * 32 + c] = fmaf(dinv[i], acc, bias[c]);
}

// layer-2 gather + fused score head (32-lane shfl reduce)
__global__ __launch_bounds__(256) void k_gather_score(
    const int* __restrict__ esrc, const int* __restrict__ rowptr,
    const float* __restrict__ dinv, const u16* __restrict__ hWs,
    const float* __restrict__ bias, const float* __restrict__ Wh,
    const float* __restrict__ bh, const float* __restrict__ cash,
    float* __restrict__ scores, int N) {
  int gid = blockIdx.x * 256 + threadIdx.x;
  if (gid == 0) scores[0] = cash[0];
  int i = gid >> 5, c = gid & 31;
  if (i >= N) return;
  float acc = bf2f(hWs[(size_t)i * 32 + c]);
  int beg = rowptr[i], end = rowptr[i + 1];
  int j = beg;
  for (; j + 3 < end; j += 4) {
    int s0 = esrc[j], s1 = esrc[j + 1], s2 = esrc[j + 2], s3 = esrc[j + 3];
    float v0 = bf2f(hWs[(size_t)s0 * 32 + c]);
    float v1 = bf2f(hWs[(size_t)s1 * 32 + c]);
    float v2 = bf2f(hWs[(size_t)s2 * 32 + c]);
    float v3 = bf2f(hWs[(size_t)s3 * 32 + c]);
    acc += (v0 + v1) + (v2 + v3);
  }
  for (; j < end; ++j) acc += bf2f(hWs[(size_t)esrc[j] * 32 + c]);
  float val = fmaf(dinv[i], acc, bias[c]);
  float t = fmaxf(val, 0.f) * Wh[c];
#pragma unroll
  for (int m = 16; m >= 1; m >>= 1) t += __shfl_xor(t, m, 32);
  if (c == 0) scores[1 + i] = t + bh[0];
}

// --- online softmax: per-block (max, sumexp) partials ---
__global__ __launch_bounds__(256) void k_sm_part(const float* __restrict__ s, int n,
                                                 float2* __restrict__ part) {
  float m = -3.4e38f, sum = 0.f;
  for (int i = blockIdx.x * 256 + threadIdx.x; i < n; i += 256 * 256) {
    float x = s[i];
    if (x > m) { sum = sum * expf(m - x) + 1.f; m = x; }
    else sum += expf(x - m);
  }
  __shared__ float sm_m[256], sm_s[256];
  sm_m[threadIdx.x] = m; sm_s[threadIdx.x] = sum;
  __syncthreads();
  for (int o = 128; o > 0; o >>= 1) {
    if (threadIdx.x < o) {
      float m1 = sm_m[threadIdx.x], s1 = sm_s[threadIdx.x];
      float m2 = sm_m[threadIdx.x + o], s2 = sm_s[threadIdx.x + o];
      float M = fmaxf(m1, m2);
      sm_s[threadIdx.x] = s1 * expf(m1 - M) + s2 * expf(m2 - M);
      sm_m[threadIdx.x] = M;
    }
    __syncthreads();
  }
  if (threadIdx.x == 0) part[blockIdx.x] = make_float2(sm_m[0], sm_s[0]);
}

__global__ __launch_bounds__(256) void k_sm_fin(const float2* __restrict__ part,
                                                float* __restrict__ finals) {
  __shared__ float sm_m[256], sm_s[256];
  float2 p = part[threadIdx.x];
  sm_m[threadIdx.x] = p.x; sm_s[threadIdx.x] = p.y;
  __syncthreads();
  for (int o = 128; o > 0; o >>= 1) {
    if (threadIdx.x < o) {
      float m1 = sm_m[threadIdx.x], s1 = sm_s[threadIdx.x];
      float m2 = sm_m[threadIdx.x + o], s2 = sm_s[threadIdx.x + o];
      float M = fmaxf(m1, m2);
      sm_s[threadIdx.x] = s1 * expf(m1 - M) + s2 * expf(m2 - M);
      sm_m[threadIdx.x] = M;
    }
    __syncthreads();
  }
  if (threadIdx.x == 0) { finals[0] = sm_m[0]; finals[1] = sm_s[0]; }
}

__global__ void k_sm_out(const float* __restrict__ s, int n,
                         const float* __restrict__ finals, float* __restrict__ out) {
  int i = blockIdx.x * 256 + threadIdx.x;
  if (i < n) out[i] = expf(s[i] - finals[0]) / finals[1];
}

extern "C" void kernel_launch(void* const* d_in, const int* in_sizes, int n_in,
                              void* d_out, int out_size, void* d_ws, size_t ws_size,
                              hipStream_t stream) {
  const float* x    = (const float*)d_in[0];
  const int*   ei   = (const int*)d_in[1];
  const float* W1   = (const float*)d_in[2];
  const float* b1   = (const float*)d_in[3];
  const float* W2   = (const float*)d_in[4];
  const float* b2   = (const float*)d_in[5];
  const float* Wh   = (const float*)d_in[6];
  const float* bh   = (const float*)d_in[7];
  const float* cash = (const float*)d_in[8];

  const int N = in_sizes[0] / 128;
  const int E = in_sizes[1] / 2;
  const int* src = ei;
  const int* dst = ei + E;
  const int nbuk = cdiv(N, 128);  // 782 for N=100000 (<= BUKMAX)

  char* p = (char*)d_ws;
  float* dinv   = (float*)p; p += sizeof(float) * N;
  u16*   hWs    = (u16*)p;   p += sizeof(u16) * (size_t)N * 32;
  float* agg    = (float*)p; p += sizeof(float) * (size_t)N * 32;
  float* scores = (float*)p; p += sizeof(float) * (N + 1);
  float2* part  = (float2*)p; p += sizeof(float2) * 256;
  float* finals = (float*)p; p += sizeof(float) * 4;
  unsigned* gcur  = (unsigned*)p; p += sizeof(unsigned) * BUKMAX;
  unsigned* bbase = (unsigned*)p; p += sizeof(unsigned) * BUKMAX;
  int* rowptr = (int*)p; p += sizeof(int) * (N + 1);
  unsigned* ebuf = (unsigned*)p; p += sizeof(unsigned) * (size_t)nbuk * CAP;
  int* esrc   = (int*)p; p += sizeof(int) * (size_t)E;
  float* out = (float*)d_out;
  const int n = N + 1;

  // --- CSR build (bucket sort; shared by both layers) ---
  (void)hipMemsetAsync(gcur, 0, sizeof(unsigned) * BUKMAX, stream);
  k_bin<<<cdiv(E, EPB), 256, 0, stream>>>(src, dst, gcur, ebuf, E, nbuk);
  k_bukscan<<<1, 1024, 0, stream>>>(gcur, bbase, rowptr, nbuk, N);
  k_place<<<nbuk, 256, 0, stream>>>(gcur, ebuf, bbase, rowptr, dinv, esrc, N);

  // --- layer 1 ---
  k_gemm1<<<cdiv((long)N * 32, 256), 256, 0, stream>>>(x, W1, dinv, hWs, N);
  k_gather<<<cdiv((long)N * 32, 256), 256, 0, stream>>>(esrc, rowptr, dinv, hWs, b1, agg, N);

  // --- layer 2 with fused score head ---
  k_gemm2<<<cdiv((long)N * 32, 256), 256, 0, stream>>>(agg, W2, dinv, hWs, N);
  k_gather_score<<<cdiv((long)N * 32, 256), 256, 0, stream>>>(
      esrc, rowptr, dinv, hWs, b2, Wh, bh, cash, scores, N);

  // --- online softmax (3 kernels) ---
  k_sm_part<<<256, 256, 0, stream>>>(scores, n, part);
  k_sm_fin<<<1, 256, 0, stream>>>(part, finals);
  k_sm_out<<<cdiv(n, 256), 256, 0, stream>>>(scores, n, finals, out);
}

// Round 12
// 273.852 us; speedup vs baseline: 5.7082x; 1.2636x over previous
//
#include <hip/hip_runtime.h>
#include <math.h>

// GCN forward: coarse-bucket counting-sort CSR + node-parallel bf16 gather.
// Measured models (R4-R11):
//   - device-scope atomic ~= 35B fabric + ~41ns chip throughput, invariant to
//     locality. k_bin traffic = fragments*line + atomics*35B: R9 (391blk x 782buk,
//     307k frags) 77MB/93us; R11 (782blk, 607k frags) 88MB/100us -> fragment
//     count is the lever => COARSE buckets (196 x 512 nodes), few blocks.
//   - gather must be node-parallel (R7), bf16 rows = 64B/edge (R11, absmax ok).
//   - scattered stores confined to block-private contiguous runs are L2-clean.
// Pipeline: k_bin (LDS hist over 196 buckets; packed (d&511)<<17|src) ->
//   k_bukscan -> k_place (196 blk x 512 thr: LDS count+scan -> rowptr/dinv,
//   in-bucket sort) -> k_gemm1 -> k_gather_fuse (layer1 gather + ReLU + W2
//   transform via __shfl, writes hWs2 bf16; gemm2 deleted) -> k_gather_score
//   (layer2 gather + score head) -> 3-kernel online softmax.

static inline int cdiv(long a, int b) { return (int)((a + (long)b - 1) / b); }

#define EPB 8192      // edges per k_bin block (391 blocks @ E=3.2M)
#define NBMAX 256     // max buckets (N <= 131072 @ 512 nodes/bucket)
#define CAP 17408     // per-bucket capacity; mean 16384, +8 sigma

typedef unsigned short u16;
typedef int iv4 __attribute__((ext_vector_type(4)));

__device__ __forceinline__ u16 f2bf(float f) {  // RNE f32->bf16
  unsigned u = __float_as_uint(f);
  return (u16)((u + 0x7FFFu + ((u >> 16) & 1u)) >> 16);
}
__device__ __forceinline__ float bf2f(u16 h) {
  return __uint_as_float(((unsigned)h) << 16);
}

// --- binning: LDS hist -> one reservation atomic per (block,bucket) -> fill runs
__global__ __launch_bounds__(256) void k_bin(const int* __restrict__ src,
                                             const int* __restrict__ dst,
                                             unsigned* __restrict__ gcur,
                                             unsigned* __restrict__ ebuf,
                                             int E, int nbuk) {
  __shared__ unsigned lhist[NBMAX];
  __shared__ unsigned lcur[NBMAX];
  int tid = threadIdx.x;
  for (int i = tid; i < nbuk; i += 256) lhist[i] = 0;
  __syncthreads();
  int e0 = blockIdx.x * EPB, e1 = min(e0 + EPB, E);
  int nvec = (e1 - e0) >> 10;  // 1024-edge chunks (256 thr x 4)
  for (int k = 0; k < nvec; ++k) {
    iv4 d4 = __builtin_nontemporal_load((const iv4*)(dst + e0 + (k << 10) + tid * 4));
    atomicAdd(&lhist[d4.x >> 9], 1u);
    atomicAdd(&lhist[d4.y >> 9], 1u);
    atomicAdd(&lhist[d4.z >> 9], 1u);
    atomicAdd(&lhist[d4.w >> 9], 1u);
  }
  for (int e = e0 + (nvec << 10) + tid; e < e1; e += 256)
    atomicAdd(&lhist[__builtin_nontemporal_load(&dst[e]) >> 9], 1u);
  __syncthreads();
  for (int b = tid; b < nbuk; b += 256) {
    unsigned nn = lhist[b];
    lcur[b] = nn ? atomicAdd(&gcur[b], nn) : 0u;  // run reservation
  }
  __syncthreads();
  for (int k = 0; k < nvec; ++k) {
    int base = e0 + (k << 10) + tid * 4;
    iv4 d4 = __builtin_nontemporal_load((const iv4*)(dst + base));
    iv4 s4 = __builtin_nontemporal_load((const iv4*)(src + base));
#define PUT(dd, ss)                                              \
    {                                                            \
      int bb = (dd) >> 9;                                        \
      unsigned off = atomicAdd(&lcur[bb], 1u);                   \
      if (off < CAP)                                             \
        ebuf[(size_t)bb * CAP + off] =                           \
            ((unsigned)((dd) & 511) << 17) | (unsigned)(ss);     \
    }
    PUT(d4.x, s4.x) PUT(d4.y, s4.y) PUT(d4.z, s4.z) PUT(d4.w, s4.w)
  }
  for (int e = e0 + (nvec << 10) + tid; e < e1; e += 256) {
    int d = __builtin_nontemporal_load(&dst[e]);
    int s = __builtin_nontemporal_load(&src[e]);
    PUT(d, s)
  }
#undef PUT
}

// --- exclusive scan of bucket counts (one block; nbuk <= 256)
__global__ __launch_bounds__(256) void k_bukscan(const unsigned* __restrict__ gcur,
                                                 unsigned* __restrict__ bbase,
                                                 int* __restrict__ rowptr,
                                                 int nbuk, int N) {
  __shared__ unsigned sm[256];
  int t = threadIdx.x;
  unsigned v = (t < nbuk) ? min(gcur[t], (unsigned)CAP) : 0u;
  sm[t] = v;
  __syncthreads();
  for (int o = 1; o < 256; o <<= 1) {
    unsigned add = (t >= o) ? sm[t - o] : 0u;
    __syncthreads();
    sm[t] += add;
    __syncthreads();
  }
  if (t < nbuk) bbase[t] = sm[t] - v;  // exclusive
  if (t == 255) rowptr[N] = (int)sm[255];
}

// --- per-bucket (512 nodes): LDS count+scan -> rowptr/dinv; sort run into esrc.
__global__ __launch_bounds__(512) void k_place(const unsigned* __restrict__ gcur,
                                               const unsigned* __restrict__ ebuf,
                                               const unsigned* __restrict__ bbase,
                                               int* __restrict__ rowptr,
                                               float* __restrict__ dinv,
                                               int* __restrict__ esrc, int N) {
  __shared__ unsigned lcnt[512];
  __shared__ unsigned lofs[512];
  int b = blockIdx.x, tid = threadIdx.x;
  lcnt[tid] = 0;
  __syncthreads();
  int cnt = min((int)gcur[b], CAP);
  const unsigned* eb = ebuf + (size_t)b * CAP;
  for (int j = tid; j < cnt; j += 512) atomicAdd(&lcnt[eb[j] >> 17], 1u);
  __syncthreads();
  unsigned myc = lcnt[tid];
  lofs[tid] = myc;
  __syncthreads();
  for (int o = 1; o < 512; o <<= 1) {  // inclusive scan over 512
    unsigned add = (tid >= o) ? lofs[tid - o] : 0u;
    __syncthreads();
    lofs[tid] += add;
    __syncthreads();
  }
  unsigned base = bbase[b];
  unsigned ex = lofs[tid] - myc;  // exclusive (own entry only)
  int node = (b << 9) + tid;
  if (node < N) {
    rowptr[node] = (int)(base + ex);
    dinv[node] = rsqrtf((float)myc + 1.0f);  // deg = cnt + self-loop
  }
  lofs[tid] = ex;  // reuse as cursor
  __syncthreads();
  for (int j = tid; j < cnt; j += 512) {
    unsigned p = eb[j];
    unsigned r = atomicAdd(&lofs[p >> 17], 1u);  // LDS atomic
    esrc[base + r] = (int)(p & 0x1FFFF);
  }
}

// hWs = bf16(dinv[r] * (x @ W1))   (x: [N,128], W1: [128,32])
__global__ __launch_bounds__(256) void k_gemm1(
    const float* __restrict__ x, const float* __restrict__ W1,
    const float* __restrict__ dinv, u16* __restrict__ hWs, int N) {
  __shared__ float w[128 * 32];
  for (int i = threadIdx.x; i < 128 * 32; i += 256) w[i] = W1[i];
  __syncthreads();
  int gid = blockIdx.x * 256 + threadIdx.x;
  int r = gid >> 5, c = gid & 31;
  if (r >= N) return;
  const float4* xr = (const float4*)(x + (size_t)r * 128);
  float acc = 0.f;
#pragma unroll
  for (int k4 = 0; k4 < 32; ++k4) {
    float4 xv = xr[k4];
    acc = fmaf(xv.x, w[(k4 * 4 + 0) * 32 + c], acc);
    acc = fmaf(xv.y, w[(k4 * 4 + 1) * 32 + c], acc);
    acc = fmaf(xv.z, w[(k4 * 4 + 2) * 32 + c], acc);
    acc = fmaf(xv.w, w[(k4 * 4 + 3) * 32 + c], acc);
  }
  hWs[gid] = f2bf(dinv[r] * acc);
}

// layer-1 gather fused with layer-2 transform:
//   r_c   = relu(b1[c] + dinv_i*(hWs1[i,c] + sum_s hWs1[s,c]))
//   hWs2[i,c] = bf16(dinv_i * sum_k r_k * W2[k,c])   (via __shfl broadcast)
__global__ __launch_bounds__(256) void k_gather_fuse(
    const int* __restrict__ esrc, const int* __restrict__ rowptr,
    const float* __restrict__ dinv, const u16* __restrict__ hWs1,
    const float* __restrict__ b1, const float* __restrict__ W2,
    u16* __restrict__ hWs2, int N) {
  __shared__ float w2[32 * 32];
  for (int i = threadIdx.x; i < 1024; i += 256) w2[i] = W2[i];
  __syncthreads();
  int gid = blockIdx.x * 256 + threadIdx.x;
  int i = gid >> 5, c = gid & 31;
  if (i >= N) return;
  float acc = bf2f(hWs1[(size_t)i * 32 + c]);
  int beg = rowptr[i], end = rowptr[i + 1];
  int j = beg;
  for (; j + 7 < end; j += 8) {
    float v0 = bf2f(hWs1[(size_t)esrc[j + 0] * 32 + c]);
    float v1 = bf2f(hWs1[(size_t)esrc[j + 1] * 32 + c]);
    float v2 = bf2f(hWs1[(size_t)esrc[j + 2] * 32 + c]);
    float v3 = bf2f(hWs1[(size_t)esrc[j + 3] * 32 + c]);
    float v4 = bf2f(hWs1[(size_t)esrc[j + 4] * 32 + c]);
    float v5 = bf2f(hWs1[(size_t)esrc[j + 5] * 32 + c]);
    float v6 = bf2f(hWs1[(size_t)esrc[j + 6] * 32 + c]);
    float v7 = bf2f(hWs1[(size_t)esrc[j + 7] * 32 + c]);
    acc += ((v0 + v1) + (v2 + v3)) + ((v4 + v5) + (v6 + v7));
  }
  for (; j < end; ++j) acc += bf2f(hWs1[(size_t)esrc[j] * 32 + c]);
  float dv = dinv[i];
  float r = fmaxf(fmaf(dv, acc, b1[c]), 0.f);
  float acc2 = 0.f;
#pragma unroll
  for (int k = 0; k < 32; ++k)
    acc2 = fmaf(__shfl(r, k, 32), w2[k * 32 + c], acc2);
  hWs2[(size_t)i * 32 + c] = f2bf(dv * acc2);
}

// layer-2 gather + fused score head (32-lane shfl reduce)
__global__ __launch_bounds__(256) void k_gather_score(
    const int* __restrict__ esrc, const int* __restrict__ rowptr,
    const float* __restrict__ dinv, const u16* __restrict__ hWs,
    const float* __restrict__ bias, const float* __restrict__ Wh,
    const float* __restrict__ bh, const float* __restrict__ cash,
    float* __restrict__ scores, int N) {
  int gid = blockIdx.x * 256 + threadIdx.x;
  if (gid == 0) scores[0] = cash[0];
  int i = gid >> 5, c = gid & 31;
  if (i >= N) return;
  float acc = bf2f(hWs[(size_t)i * 32 + c]);
  int beg = rowptr[i], end = rowptr[i + 1];
  int j = beg;
  for (; j + 7 < end; j += 8) {
    float v0 = bf2f(hWs[(size_t)esrc[j + 0] * 32 + c]);
    float v1 = bf2f(hWs[(size_t)esrc[j + 1] * 32 + c]);
    float v2 = bf2f(hWs[(size_t)esrc[j + 2] * 32 + c]);
    float v3 = bf2f(hWs[(size_t)esrc[j + 3] * 32 + c]);
    float v4 = bf2f(hWs[(size_t)esrc[j + 4] * 32 + c]);
    float v5 = bf2f(hWs[(size_t)esrc[j + 5] * 32 + c]);
    float v6 = bf2f(hWs[(size_t)esrc[j + 6] * 32 + c]);
    float v7 = bf2f(hWs[(size_t)esrc[j + 7] * 32 + c]);
    acc += ((v0 + v1) + (v2 + v3)) + ((v4 + v5) + (v6 + v7));
  }
  for (; j < end; ++j) acc += bf2f(hWs[(size_t)esrc[j] * 32 + c]);
  float val = fmaf(dinv[i], acc, bias[c]);
  float t = fmaxf(val, 0.f) * Wh[c];
#pragma unroll
  for (int m = 16; m >= 1; m >>= 1) t += __shfl_xor(t, m, 32);
  if (c == 0) scores[1 + i] = t + bh[0];
}

// --- online softmax: per-block (max, sumexp) partials ---
__global__ __launch_bounds__(256) void k_sm_part(const float* __restrict__ s, int n,
                                                 float2* __restrict__ part) {
  float m = -3.4e38f, sum = 0.f;
  for (int i = blockIdx.x * 256 + threadIdx.x; i < n; i += 256 * 256) {
    float x = s[i];
    if (x > m) { sum = sum * expf(m - x) + 1.f; m = x; }
    else sum += expf(x - m);
  }
  __shared__ float sm_m[256], sm_s[256];
  sm_m[threadIdx.x] = m; sm_s[threadIdx.x] = sum;
  __syncthreads();
  for (int o = 128; o > 0; o >>= 1) {
    if (threadIdx.x < o) {
      float m1 = sm_m[threadIdx.x], s1 = sm_s[threadIdx.x];
      float m2 = sm_m[threadIdx.x + o], s2 = sm_s[threadIdx.x + o];
      float M = fmaxf(m1, m2);
      sm_s[threadIdx.x] = s1 * expf(m1 - M) + s2 * expf(m2 - M);
      sm_m[threadIdx.x] = M;
    }
    __syncthreads();
  }
  if (threadIdx.x == 0) part[blockIdx.x] = make_float2(sm_m[0], sm_s[0]);
}

__global__ __launch_bounds__(256) void k_sm_fin(const float2* __restrict__ part,
                                                float* __restrict__ finals) {
  __shared__ float sm_m[256], sm_s[256];
  float2 p = part[threadIdx.x];
  sm_m[threadIdx.x] = p.x; sm_s[threadIdx.x] = p.y;
  __syncthreads();
  for (int o = 128; o > 0; o >>= 1) {
    if (threadIdx.x < o) {
      float m1 = sm_m[threadIdx.x], s1 = sm_s[threadIdx.x];
      float m2 = sm_m[threadIdx.x + o], s2 = sm_s[threadIdx.x + o];
      float M = fmaxf(m1, m2);
      sm_s[threadIdx.x] = s1 * expf(m1 - M) + s2 * expf(m2 - M);
      sm_m[threadIdx.x] = M;
    }
    __syncthreads();
  }
  if (threadIdx.x == 0) { finals[0] = sm_m[0]; finals[1] = sm_s[0]; }
}

__global__ void k_sm_out(const float* __restrict__ s, int n,
                         const float* __restrict__ finals, float* __restrict__ out) {
  int i = blockIdx.x * 256 + threadIdx.x;
  if (i < n) out[i] = expf(s[i] - finals[0]) / finals[1];
}

extern "C" void kernel_launch(void* const* d_in, const int* in_sizes, int n_in,
                              void* d_out, int out_size, void* d_ws, size_t ws_size,
                              hipStream_t stream) {
  const float* x    = (const float*)d_in[0];
  const int*   ei   = (const int*)d_in[1];
  const float* W1   = (const float*)d_in[2];
  const float* b1   = (const float*)d_in[3];
  const float* W2   = (const float*)d_in[4];
  const float* b2   = (const float*)d_in[5];
  const float* Wh   = (const float*)d_in[6];
  const float* bh   = (const float*)d_in[7];
  const float* cash = (const float*)d_in[8];

  const int N = in_sizes[0] / 128;
  const int E = in_sizes[1] / 2;
  const int* src = ei;
  const int* dst = ei + E;
  const int nbuk = cdiv(N, 512);  // 196 for N=100000 (<= NBMAX)

  char* p = (char*)d_ws;
  float* dinv   = (float*)p; p += sizeof(float) * N;
  u16*   hWs1   = (u16*)p;   p += sizeof(u16) * (size_t)N * 32;
  u16*   hWs2   = (u16*)p;   p += sizeof(u16) * (size_t)N * 32;
  float* scores = (float*)p; p += sizeof(float) * (N + 1);
  float2* part  = (float2*)p; p += sizeof(float2) * 256;
  float* finals = (float*)p; p += sizeof(float) * 4;
  unsigned* gcur  = (unsigned*)p; p += sizeof(unsigned) * NBMAX;
  unsigned* bbase = (unsigned*)p; p += sizeof(unsigned) * NBMAX;
  int* rowptr = (int*)p; p += sizeof(int) * (N + 1);
  unsigned* ebuf = (unsigned*)p; p += sizeof(unsigned) * (size_t)nbuk * CAP;
  int* esrc   = (int*)p; p += sizeof(int) * (size_t)E;
  float* out = (float*)d_out;
  const int n = N + 1;

  // --- CSR build (coarse-bucket counting sort; shared by both layers) ---
  (void)hipMemsetAsync(gcur, 0, sizeof(unsigned) * NBMAX, stream);
  k_bin<<<cdiv(E, EPB), 256, 0, stream>>>(src, dst, gcur, ebuf, E, nbuk);
  k_bukscan<<<1, 256, 0, stream>>>(gcur, bbase, rowptr, nbuk, N);
  k_place<<<nbuk, 512, 0, stream>>>(gcur, ebuf, bbase, rowptr, dinv, esrc, N);

  // --- layer 1 (+ fused layer-2 transform) ---
  k_gemm1<<<cdiv((long)N * 32, 256), 256, 0, stream>>>(x, W1, dinv, hWs1, N);
  k_gather_fuse<<<cdiv((long)N * 32, 256), 256, 0, stream>>>(
      esrc, rowptr, dinv, hWs1, b1, W2, hWs2, N);

  // --- layer 2 gather + fused score head ---
  k_gather_score<<<cdiv((long)N * 32, 256), 256, 0, stream>>>(
      esrc, rowptr, dinv, hWs2, b2, Wh, bh, cash, scores, N);

  // --- online softmax (3 kernels) ---
  k_sm_part<<<256, 256, 0, stream>>>(scores, n, part);
  k_sm_fin<<<1, 256, 0, stream>>>(part, finals);
  k_sm_out<<<cdiv(n, 256), 256, 0, stream>>>(scores, n, finals, out);
}